// Round 4
// baseline (639.499 us; speedup 1.0000x reference)
//
#include <hip/hip_runtime.h>
#include <hip/hip_bf16.h>

// Problem shapes (fixed by setup_inputs)
#define B_    1024
#define D_    768
#define POOL_ 100
#define PLEN_ 8
#define TOPK_ 3
#define EK_ELEMS (B_ * 4 * D_)           // 3,145,728
#define XB_ELEMS (B_ * 197 * D_)         // 154,976,256
#define XB_F4    (XB_ELEMS / 4)          // 38,744,064 float4s

#define SCORE_BLOCKS 128
#define COPY_BLOCKS  896
#define NBLOCKS      (SCORE_BLOCKS + COPY_BLOCKS)   // 1024
#define ROWS_PER_SB  (B_ / SCORE_BLOCKS)            // 8

typedef float f4_t __attribute__((ext_vector_type(4)));

// ---------------------------------------------------------------------------
// Kernel 1: per-pool-row prep: sm[k,:] = softmax(A[k,:]) (f64),
//           nK[k,:] = K[k,:] / max(||K[k,:]||, 1e-12)   (f64)
// grid = POOL_ blocks, 256 threads. ~8 us total; runs before the fused kernel.
// ---------------------------------------------------------------------------
__global__ void prep_kernel(const float* __restrict__ A, const float* __restrict__ K,
                            double* __restrict__ sm, double* __restrict__ nK) {
    const int k = blockIdx.x;
    const int t = threadIdx.x;
    const int wave = t >> 6, lane = t & 63;
    __shared__ double red[4];

    // ---- max of A row ----
    double m = -1e300;
    for (int d = t; d < D_; d += 256) m = fmax(m, (double)A[k * D_ + d]);
    #pragma unroll
    for (int off = 32; off >= 1; off >>= 1) m = fmax(m, __shfl_xor(m, off));
    if (lane == 0) red[wave] = m;
    __syncthreads();
    m = fmax(fmax(red[0], red[1]), fmax(red[2], red[3]));
    __syncthreads();

    // ---- sum of exp ----
    double s = 0.0;
    for (int d = t; d < D_; d += 256) s += exp((double)A[k * D_ + d] - m);
    #pragma unroll
    for (int off = 32; off >= 1; off >>= 1) s += __shfl_xor(s, off);
    if (lane == 0) red[wave] = s;
    __syncthreads();
    s = red[0] + red[1] + red[2] + red[3];
    __syncthreads();

    for (int d = t; d < D_; d += 256)
        sm[k * D_ + d] = exp((double)A[k * D_ + d] - m) / s;

    // ---- K row L2 norm ----
    double ss = 0.0;
    for (int d = t; d < D_; d += 256) {
        double v = (double)K[k * D_ + d];
        ss += v * v;
    }
    #pragma unroll
    for (int off = 32; off >= 1; off >>= 1) ss += __shfl_xor(ss, off);
    if (lane == 0) red[wave] = ss;
    __syncthreads();
    ss = red[0] + red[1] + red[2] + red[3];
    const double n = fmax(sqrt(ss), 1e-12);

    for (int d = t; d < D_; d += 256)
        nK[k * D_ + d] = (double)K[k * D_ + d] / n;
}

// ---------------------------------------------------------------------------
// Kernel 2 (fused, STATIC partition, zero atomics):
//   blocks [0, 128):   score+top3+gather for 8 contiguous b-rows each.
//                      All operands (sm/nK 1.2 MB, p 2.4 MB) are L2-resident;
//                      ~50 us total, hidden under the copy.
//   blocks [128,1024): grid-stride nontemporal float4 copy of x_block
//                      (620 MB read + 620 MB write) into the tail of out.
//                      896 blocks = 3584 waves -> HBM-saturating.
// R3 lesson: a single-cache-line atomic task queue (20K claims, 8 XCDs)
// serialized the whole kernel (~85 ns/claim -> 1.7 ms). Static roles instead.
// ---------------------------------------------------------------------------
__global__ void __launch_bounds__(256, 4)
fused_kernel(const float* __restrict__ xq, const float* __restrict__ xb,
             const double* __restrict__ sm, const double* __restrict__ nK,
             const float* __restrict__ p, float* __restrict__ out) {
    const int t = threadIdx.x;

    if (blockIdx.x >= SCORE_BLOCKS) {
        // ---------------- copy role ----------------
        const f4_t* __restrict__ src = (const f4_t*)xb;
        f4_t* __restrict__ dst = (f4_t*)(out + 2 * (size_t)EK_ELEMS);
        size_t i = (size_t)(blockIdx.x - SCORE_BLOCKS) * 256 + t;
        const size_t stride = (size_t)COPY_BLOCKS * 256;
        for (; i < (size_t)XB_F4; i += stride) {
            f4_t v = __builtin_nontemporal_load(&src[i]);
            __builtin_nontemporal_store(v, &dst[i]);
        }
        return;
    }

    // ---------------- score role ----------------
    __shared__ double s_xq[D_];
    __shared__ double s_aq[POOL_];
    __shared__ int    s_idx[TOPK_];
    const int wave = t >> 6, lane = t & 63;

    for (int r = 0; r < ROWS_PER_SB; ++r) {
        const int b = blockIdx.x * ROWS_PER_SB + r;

        __syncthreads();   // protect s_xq/s_aq reuse across rows
        for (int d = t; d < D_; d += 256) s_xq[d] = (double)xq[b * D_ + d];
        __syncthreads();

        for (int k = wave; k < POOL_; k += 4) {
            const double* __restrict__ smk = sm + (size_t)k * D_;
            const double* __restrict__ nkk = nK + (size_t)k * D_;
            double dot = 0.0, sq = 0.0;
            for (int d = lane; d < D_; d += 64) {
                double v = s_xq[d] * smk[d];
                dot += v * nkk[d];
                sq  += v * v;
            }
            #pragma unroll
            for (int off = 32; off >= 1; off >>= 1) {
                dot += __shfl_xor(dot, off);
                sq  += __shfl_xor(sq, off);
            }
            if (lane == 0) s_aq[k] = dot / fmax(sqrt(sq), 1e-12);
        }
        __syncthreads();

        if (t == 0) {
            // top-3, ties -> lowest index (lax.top_k is stable)
            #pragma unroll
            for (int rr = 0; rr < TOPK_; ++rr) {
                double best = -1e300; int bi = 0;
                for (int kk = 0; kk < POOL_; ++kk)
                    if (s_aq[kk] > best) { best = s_aq[kk]; bi = kk; }
                s_idx[rr] = bi;
                s_aq[bi] = -1e300;
            }
        }
        __syncthreads();
        const int i0 = s_idx[0], i1 = s_idx[1], i2 = s_idx[2];

        // gather: 8 prompt-rows x 192 float4 = 1536 units over 256 threads
        for (int w = t; w < PLEN_ * 192; w += 256) {
            const int j = w / 192, c = w % 192;
            const f4_t* __restrict__ q0 = (const f4_t*)(p + (size_t)(j * POOL_ + i0) * D_);
            const f4_t* __restrict__ q1 = (const f4_t*)(p + (size_t)(j * POOL_ + i1) * D_);
            const f4_t* __restrict__ q2 = (const f4_t*)(p + (size_t)(j * POOL_ + i2) * D_);
            f4_t v = q0[c] + q1[c] + q2[c];
            float* dst = (j < 4) ? out + ((size_t)b * 4 + j) * D_
                                 : out + EK_ELEMS + ((size_t)b * 4 + (j - 4)) * D_;
            ((f4_t*)dst)[c] = v;
        }
    }
}

extern "C" void kernel_launch(void* const* d_in, const int* in_sizes, int n_in,
                              void* d_out, int out_size, void* d_ws, size_t ws_size,
                              hipStream_t stream) {
    const float* x_querry = (const float*)d_in[0];   // (1024, 768)
    const float* x_block  = (const float*)d_in[1];   // (1024, 197, 768)
    const float* K        = (const float*)d_in[2];   // (100, 768)
    const float* A        = (const float*)d_in[3];   // (100, 768)
    const float* p        = (const float*)d_in[4];   // (8, 100, 768)
    // d_in[5] = l (unused)

    float* out = (float*)d_out;

    // workspace layout
    double* sm = (double*)d_ws;                 // 100*768 f64 = 614400 B
    double* nK = sm + (size_t)POOL_ * D_;       // 614400 B

    prep_kernel<<<POOL_, 256, 0, stream>>>(A, K, sm, nK);
    fused_kernel<<<NBLOCKS, 256, 0, stream>>>(x_querry, x_block, sm, nK, p, out);
}

// Round 5
// 574.019 us; speedup vs baseline: 1.1141x; 1.1141x over previous
//
#include <hip/hip_runtime.h>
#include <hip/hip_bf16.h>

// Problem shapes (fixed by setup_inputs)
#define B_    1024
#define D_    768
#define POOL_ 100
#define PLEN_ 8
#define TOPK_ 3
#define EK_ELEMS (B_ * 4 * D_)           // 3,145,728
#define XB_ELEMS (B_ * 197 * D_)         // 154,976,256
#define XB_F4    (XB_ELEMS / 4)          // 38,744,064 float4s

#define SCORE_BLOCKS 256
#define COPY_BLOCKS  3840
#define NBLOCKS      (SCORE_BLOCKS + COPY_BLOCKS)   // 4096
#define ROWS_PER_SB  (B_ / SCORE_BLOCKS)            // 4

typedef float f4_t __attribute__((ext_vector_type(4)));

// ---------------------------------------------------------------------------
// Kernel 1: per-pool-row prep: sm[k,:] = softmax(A[k,:]) (f64),
//           nK[k,:] = K[k,:] / max(||K[k,:]||, 1e-12)   (f64)
// grid = POOL_ blocks, 256 threads. ~8 us; runs before the fused kernel.
// ---------------------------------------------------------------------------
__global__ void prep_kernel(const float* __restrict__ A, const float* __restrict__ K,
                            double* __restrict__ sm, double* __restrict__ nK) {
    const int k = blockIdx.x;
    const int t = threadIdx.x;
    const int wave = t >> 6, lane = t & 63;
    __shared__ double red[4];

    double m = -1e300;
    for (int d = t; d < D_; d += 256) m = fmax(m, (double)A[k * D_ + d]);
    #pragma unroll
    for (int off = 32; off >= 1; off >>= 1) m = fmax(m, __shfl_xor(m, off));
    if (lane == 0) red[wave] = m;
    __syncthreads();
    m = fmax(fmax(red[0], red[1]), fmax(red[2], red[3]));
    __syncthreads();

    double s = 0.0;
    for (int d = t; d < D_; d += 256) s += exp((double)A[k * D_ + d] - m);
    #pragma unroll
    for (int off = 32; off >= 1; off >>= 1) s += __shfl_xor(s, off);
    if (lane == 0) red[wave] = s;
    __syncthreads();
    s = red[0] + red[1] + red[2] + red[3];
    __syncthreads();

    for (int d = t; d < D_; d += 256)
        sm[k * D_ + d] = exp((double)A[k * D_ + d] - m) / s;

    double ss = 0.0;
    for (int d = t; d < D_; d += 256) {
        double v = (double)K[k * D_ + d];
        ss += v * v;
    }
    #pragma unroll
    for (int off = 32; off >= 1; off >>= 1) ss += __shfl_xor(ss, off);
    if (lane == 0) red[wave] = ss;
    __syncthreads();
    ss = red[0] + red[1] + red[2] + red[3];
    const double n = fmax(sqrt(ss), 1e-12);

    for (int d = t; d < D_; d += 256)
        nK[k * D_ + d] = (double)K[k * D_ + d] / n;
}

// ---------------------------------------------------------------------------
// Kernel 2 (fused, static partition, zero atomics):
//   blocks [0, 256):    score+top3+gather for 4 b-rows each (L2-resident
//                       operands; hidden under the copy).
//   blocks [256, 4096): grid-stride PLAIN float4 copy of x_block, 4x batched
//                       loads/stores to keep >=4 requests in flight per wave.
// R3 lesson: no atomic work queues (cross-XCD line bounce serializes).
// R4 lesson: NT hints + low occupancy halved copy BW; harness fill and m13
//            float4 copy (no NT, full occupancy) both run ~6.3-6.9 TB/s.
// Oversubscription (4096 blocks) re-fills CU slots as score blocks retire.
// ---------------------------------------------------------------------------
__global__ void __launch_bounds__(256)
fused_kernel(const float* __restrict__ xq, const float* __restrict__ xb,
             const double* __restrict__ sm, const double* __restrict__ nK,
             const float* __restrict__ p, float* __restrict__ out) {
    const int t = threadIdx.x;

    if (blockIdx.x >= SCORE_BLOCKS) {
        // ---------------- copy role ----------------
        const f4_t* __restrict__ src = (const f4_t*)xb;
        f4_t* __restrict__ dst = (f4_t*)(out + 2 * (size_t)EK_ELEMS);
        const size_t stride = (size_t)COPY_BLOCKS * 256;
        size_t i = (size_t)(blockIdx.x - SCORE_BLOCKS) * 256 + t;
        for (; i + 3 * stride < (size_t)XB_F4; i += 4 * stride) {
            f4_t a = src[i];
            f4_t b = src[i + stride];
            f4_t c = src[i + 2 * stride];
            f4_t d = src[i + 3 * stride];
            dst[i]              = a;
            dst[i + stride]     = b;
            dst[i + 2 * stride] = c;
            dst[i + 3 * stride] = d;
        }
        for (; i < (size_t)XB_F4; i += stride)
            dst[i] = src[i];
        return;
    }

    // ---------------- score role ----------------
    __shared__ double s_xq[D_];
    __shared__ double s_aq[POOL_];
    __shared__ int    s_idx[TOPK_];
    const int wave = t >> 6, lane = t & 63;

    for (int r = 0; r < ROWS_PER_SB; ++r) {
        const int b = blockIdx.x * ROWS_PER_SB + r;

        __syncthreads();   // protect s_xq/s_aq reuse across rows
        for (int d = t; d < D_; d += 256) s_xq[d] = (double)xq[b * D_ + d];
        __syncthreads();

        for (int k = wave; k < POOL_; k += 4) {
            const double* __restrict__ smk = sm + (size_t)k * D_;
            const double* __restrict__ nkk = nK + (size_t)k * D_;
            double dot = 0.0, sq = 0.0;
            for (int d = lane; d < D_; d += 64) {
                double v = s_xq[d] * smk[d];
                dot += v * nkk[d];
                sq  += v * v;
            }
            #pragma unroll
            for (int off = 32; off >= 1; off >>= 1) {
                dot += __shfl_xor(dot, off);
                sq  += __shfl_xor(sq, off);
            }
            if (lane == 0) s_aq[k] = dot / fmax(sqrt(sq), 1e-12);
        }
        __syncthreads();

        if (t == 0) {
            // top-3, ties -> lowest index (lax.top_k is stable)
            #pragma unroll
            for (int rr = 0; rr < TOPK_; ++rr) {
                double best = -1e300; int bi = 0;
                for (int kk = 0; kk < POOL_; ++kk)
                    if (s_aq[kk] > best) { best = s_aq[kk]; bi = kk; }
                s_idx[rr] = bi;
                s_aq[bi] = -1e300;
            }
        }
        __syncthreads();
        const int i0 = s_idx[0], i1 = s_idx[1], i2 = s_idx[2];

        // gather: 8 prompt-rows x 192 float4 = 1536 units over 256 threads
        for (int w = t; w < PLEN_ * 192; w += 256) {
            const int j = w / 192, c = w % 192;
            const f4_t* __restrict__ q0 = (const f4_t*)(p + (size_t)(j * POOL_ + i0) * D_);
            const f4_t* __restrict__ q1 = (const f4_t*)(p + (size_t)(j * POOL_ + i1) * D_);
            const f4_t* __restrict__ q2 = (const f4_t*)(p + (size_t)(j * POOL_ + i2) * D_);
            f4_t v = q0[c] + q1[c] + q2[c];
            float* dst = (j < 4) ? out + ((size_t)b * 4 + j) * D_
                                 : out + EK_ELEMS + ((size_t)b * 4 + (j - 4)) * D_;
            ((f4_t*)dst)[c] = v;
        }
    }
}

extern "C" void kernel_launch(void* const* d_in, const int* in_sizes, int n_in,
                              void* d_out, int out_size, void* d_ws, size_t ws_size,
                              hipStream_t stream) {
    const float* x_querry = (const float*)d_in[0];   // (1024, 768)
    const float* x_block  = (const float*)d_in[1];   // (1024, 197, 768)
    const float* K        = (const float*)d_in[2];   // (100, 768)
    const float* A        = (const float*)d_in[3];   // (100, 768)
    const float* p        = (const float*)d_in[4];   // (8, 100, 768)
    // d_in[5] = l (unused)

    float* out = (float*)d_out;

    // workspace layout
    double* sm = (double*)d_ws;                 // 100*768 f64 = 614400 B
    double* nK = sm + (size_t)POOL_ * D_;       // 614400 B

    prep_kernel<<<POOL_, 256, 0, stream>>>(A, K, sm, nK);
    fused_kernel<<<NBLOCKS, 256, 0, stream>>>(x_querry, x_block, sm, nK, p, out);
}

// Round 6
// 383.037 us; speedup vs baseline: 1.6696x; 1.4986x over previous
//
#include <hip/hip_runtime.h>
#include <hip/hip_bf16.h>

// Problem shapes (fixed by setup_inputs)
#define B_    1024
#define D_    768
#define POOL_ 100
#define PLEN_ 8
#define TOPK_ 3
#define EK_ELEMS (B_ * 4 * D_)           // 3,145,728
#define XB_ELEMS (B_ * 197 * D_)         // 154,976,256
#define XB_F4    (XB_ELEMS / 4)          // 38,744,064 float4s
#define COPY_BLOCKS 8192

typedef float f4_t __attribute__((ext_vector_type(4)));

// ---------------------------------------------------------------------------
// Kernel 1: per-pool-row prep: sm[k,:] = softmax(A[k,:]) (f64),
//           nK[k,:] = K[k,:] / max(||K[k,:]||, 1e-12)   (f64)
// ---------------------------------------------------------------------------
__global__ void prep_kernel(const float* __restrict__ A, const float* __restrict__ K,
                            double* __restrict__ sm, double* __restrict__ nK) {
    const int k = blockIdx.x;
    const int t = threadIdx.x;
    const int wave = t >> 6, lane = t & 63;
    __shared__ double red[4];

    double m = -1e300;
    for (int d = t; d < D_; d += 256) m = fmax(m, (double)A[k * D_ + d]);
    #pragma unroll
    for (int off = 32; off >= 1; off >>= 1) m = fmax(m, __shfl_xor(m, off));
    if (lane == 0) red[wave] = m;
    __syncthreads();
    m = fmax(fmax(red[0], red[1]), fmax(red[2], red[3]));
    __syncthreads();

    double s = 0.0;
    for (int d = t; d < D_; d += 256) s += exp((double)A[k * D_ + d] - m);
    #pragma unroll
    for (int off = 32; off >= 1; off >>= 1) s += __shfl_xor(s, off);
    if (lane == 0) red[wave] = s;
    __syncthreads();
    s = red[0] + red[1] + red[2] + red[3];
    __syncthreads();

    for (int d = t; d < D_; d += 256)
        sm[k * D_ + d] = exp((double)A[k * D_ + d] - m) / s;

    double ss = 0.0;
    for (int d = t; d < D_; d += 256) {
        double v = (double)K[k * D_ + d];
        ss += v * v;
    }
    #pragma unroll
    for (int off = 32; off >= 1; off >>= 1) ss += __shfl_xor(ss, off);
    if (lane == 0) red[wave] = ss;
    __syncthreads();
    ss = red[0] + red[1] + red[2] + red[3];
    const double n = fmax(sqrt(ss), 1e-12);

    for (int d = t; d < D_; d += 256)
        nK[k * D_ + d] = (double)K[k * D_ + d] / n;
}

// ---------------------------------------------------------------------------
// Kernel 2: score + wave-parallel top-3 + gather, one block per b-row.
// idx never touches global memory. Top-3 via shuffle-reduce argmax
// (3 passes, tie -> lowest index, matching lax.top_k stability) instead of
// the old serial t==0 loop (300 dependent ~120cyc LDS loads ~ 15us/block).
// ---------------------------------------------------------------------------
__global__ void __launch_bounds__(256)
score_gather_kernel(const float* __restrict__ xq,
                    const double* __restrict__ sm,
                    const double* __restrict__ nK,
                    const float* __restrict__ p,
                    float* __restrict__ out) {
    __shared__ double s_xq[D_];
    __shared__ double s_aq[POOL_];
    __shared__ int    s_idx[TOPK_];
    const int b = blockIdx.x;
    const int t = threadIdx.x;
    const int wave = t >> 6, lane = t & 63;

    for (int d = t; d < D_; d += 256) s_xq[d] = (double)xq[b * D_ + d];
    __syncthreads();

    for (int k = wave; k < POOL_; k += 4) {
        const double* __restrict__ smk = sm + (size_t)k * D_;
        const double* __restrict__ nkk = nK + (size_t)k * D_;
        double dot = 0.0, sq = 0.0;
        for (int d = lane; d < D_; d += 64) {
            double v = s_xq[d] * smk[d];
            dot += v * nkk[d];
            sq  += v * v;
        }
        #pragma unroll
        for (int off = 32; off >= 1; off >>= 1) {
            dot += __shfl_xor(dot, off);
            sq  += __shfl_xor(sq, off);
        }
        if (lane == 0) s_aq[k] = dot / fmax(sqrt(sq), 1e-12);
    }
    __syncthreads();

    if (wave == 0) {
        // lane covers k = lane and k = lane+64
        double v0 = (lane < POOL_) ? s_aq[lane] : -1e300;
        double v1 = (lane + 64 < POOL_) ? s_aq[lane + 64] : -1e300;
        #pragma unroll
        for (int r = 0; r < TOPK_; ++r) {
            double v; int ki;
            if (v0 >= v1) { v = v0; ki = lane; }       // tie -> lower index
            else          { v = v1; ki = lane + 64; }
            #pragma unroll
            for (int off = 32; off >= 1; off >>= 1) {
                double ov = __shfl_xor(v, off);
                int    oi = __shfl_xor(ki, off);
                if (ov > v || (ov == v && oi < ki)) { v = ov; ki = oi; }
            }
            if (lane == 0) s_idx[r] = ki;
            if (ki == lane)      v0 = -1e300;
            if (ki == lane + 64) v1 = -1e300;
        }
    }
    __syncthreads();
    const int i0 = s_idx[0], i1 = s_idx[1], i2 = s_idx[2];

    // gather: 8 prompt-rows x 192 float4 = 1536 units over 256 threads
    for (int w = t; w < PLEN_ * 192; w += 256) {
        const int j = w / 192, c = w % 192;
        const f4_t* __restrict__ q0 = (const f4_t*)(p + (size_t)(j * POOL_ + i0) * D_);
        const f4_t* __restrict__ q1 = (const f4_t*)(p + (size_t)(j * POOL_ + i1) * D_);
        const f4_t* __restrict__ q2 = (const f4_t*)(p + (size_t)(j * POOL_ + i2) * D_);
        f4_t v = q0[c] + q1[c] + q2[c];
        float* dst = (j < 4) ? out + ((size_t)b * 4 + j) * D_
                             : out + EK_ELEMS + ((size_t)b * 4 + (j - 4)) * D_;
        ((f4_t*)dst)[c] = v;
    }
}

// ---------------------------------------------------------------------------
// Kernel 3: pure x_block passthrough. m13-clone: plain grid-stride float4,
// no NT hints, no LDS, dedicated dispatch.
// R4/R5 lesson: mixed-role dispatches capped at ~2 TB/s regardless of block
// split; dedicated copy is the only configuration with a measured 6.3 TB/s
// precedent (m13) on this part.
// ---------------------------------------------------------------------------
__global__ void __launch_bounds__(256)
copy_kernel(const f4_t* __restrict__ src, f4_t* __restrict__ dst) {
    size_t i = (size_t)blockIdx.x * 256 + threadIdx.x;
    const size_t stride = (size_t)COPY_BLOCKS * 256;
    for (; i < (size_t)XB_F4; i += stride)
        dst[i] = src[i];
}

extern "C" void kernel_launch(void* const* d_in, const int* in_sizes, int n_in,
                              void* d_out, int out_size, void* d_ws, size_t ws_size,
                              hipStream_t stream) {
    const float* x_querry = (const float*)d_in[0];   // (1024, 768)
    const float* x_block  = (const float*)d_in[1];   // (1024, 197, 768)
    const float* K        = (const float*)d_in[2];   // (100, 768)
    const float* A        = (const float*)d_in[3];   // (100, 768)
    const float* p        = (const float*)d_in[4];   // (8, 100, 768)
    // d_in[5] = l (unused)

    float* out = (float*)d_out;

    // workspace layout
    double* sm = (double*)d_ws;                 // 100*768 f64 = 614400 B
    double* nK = sm + (size_t)POOL_ * D_;       // 614400 B

    prep_kernel<<<POOL_, 256, 0, stream>>>(A, K, sm, nK);
    score_gather_kernel<<<B_, 256, 0, stream>>>(x_querry, sm, nK, p, out);
    copy_kernel<<<COPY_BLOCKS, 256, 0, stream>>>(
        (const f4_t*)x_block, (f4_t*)(out + 2 * (size_t)EK_ELEMS));
}